// Round 13
// baseline (36.050 us; speedup 1.0000x reference)
//
#include <hip/hip_runtime.h>

#define IMG_H 1024
#define IMG_W 1024
#define NIMG  16
#define NPIX  16777216.0f   // 16*1024*1024
#define NBLK  4096          // 256 4-row strips per image; 4 autonomous waves/block
#define LOG2E 1.44269504088896340736f
#define LN2   0.69314718055994530942f

#ifndef __has_builtin
#define __has_builtin(x) 0
#endif

// Async global->LDS. dst is WAVE-UNIFORM base; HW adds lane*size.
// src is per-lane global address. Zero VGPR round-trip.
__device__ __forceinline__ void stage16(const float* src, float* dstLds) {
#if __has_builtin(__builtin_amdgcn_global_load_lds)
    __builtin_amdgcn_global_load_lds(
        (const __attribute__((address_space(1))) void*)src,
        (__attribute__((address_space(3))) void*)dstLds, 16, 0, 0);
#endif
}
__device__ __forceinline__ void stage4(const float* src, float* dstLds) {
#if __has_builtin(__builtin_amdgcn_global_load_lds)
    __builtin_amdgcn_global_load_lds(
        (const __attribute__((address_space(1))) void*)src,
        (__attribute__((address_space(3))) void*)dstLds, 4, 0, 0);
#endif
}

// ws layout: one float4 per WAVE {bce, inter, sum_p, sum_t}.
// slot = b*4 + wid; 16384 slots * 16B = 256 KB.

__global__ __launch_bounds__(256, 6) void dal_main(
    const float* __restrict__ xlogits,
    const float* __restrict__ gmask,
    const float* __restrict__ fuse,
    float4* __restrict__ ws4)
{
    // per-wave LDS: [0..63] halo staging, [64..1599] 6 rows x 256 cols
    __shared__ float lds[4 * 1600];     // 25600 B -> 6 blocks/CU, 24 waves/CU

    // XCD-chunked bijective swizzle (4096 % 8 == 0)
    const int bid = blockIdx.x;
    const int b   = (bid & 7) * (NBLK / 8) + (bid >> 3);

    const int img    = b >> 8;          // 256 strips per image
    const int r0     = (b & 255) << 2;  // rows r0 .. r0+3, r0 % 4 == 0
    const int tid    = (int)threadIdx.x;
    const int wid    = tid >> 6;
    const int lane   = tid & 63;
    const int wstart = wid << 8;        // wave's col range [wstart, wstart+256)
    const int jg     = wstart + (lane << 2);   // this thread's 4 cols

    const float w0 = fuse[0], w1 = fuse[1], w2 = fuse[2];

    const size_t ibase = (size_t)img * (IMG_H * IMG_W);
    const float* gi = gmask + ibase;
    const float* xi = xlogits + ibase;

    float* wlds = &lds[wid * 1600];

    // ---- stage 6 mask rows (r0-1 .. r0+4), clamped; pad fixed later
    #pragma unroll
    for (int t = 0; t < 6; ++t) {
        int r  = r0 - 1 + t;
        int rc = r < 0 ? 0 : (r > IMG_H - 1 ? IMG_H - 1 : r);
        stage16(gi + (size_t)rc * IMG_W + jg, wlds + 64 + t * 256);
    }
    // ---- stage halo columns: lanes 0-5 left col (rows r0-1..r0+4),
    //      lanes 6-11 right col, others dummy. halo[lane] <- value.
    {
        int t6 = (lane < 6) ? lane : ((lane < 12) ? lane - 6 : 1);
        int rh = r0 - 1 + t6;
        rh = rh < 0 ? 0 : (rh > IMG_H - 1 ? IMG_H - 1 : rh);
        int ch = wstart;                                              // dummy
        ch = (lane < 12) ? ((wstart + 256 < IMG_W) ? wstart + 256 : IMG_W - 1) : ch;
        ch = (lane < 6)  ? ((wstart > 0) ? wstart - 1 : 0)                    : ch;
        stage4(gi + (size_t)rh * IMG_W + ch, wlds);
    }

    // ---- logits loads (registers; same vmcnt domain)
    float4 xv[4];
    const float* xr = xi + (size_t)r0 * IMG_W + jg;
    #pragma unroll
    for (int r = 0; r < 4; ++r)
        xv[r] = *reinterpret_cast<const float4*>(xr + (size_t)r * IMG_W);

    // wave-local drain; NO __syncthreads anywhere (waves fully autonomous)
    asm volatile("s_waitcnt vmcnt(0)" ::: "memory");
    __builtin_amdgcn_sched_barrier(0);

    // ---- fold rows from LDS: rowmin over (jg+k-1 .. jg+k+1) + centers
    const bool hasL = (wstart > 0);              // wave 0: image left edge
    const bool hasR = (wstart + 256 < IMG_W);    // wave 3: image right edge
    const int  bl   = lane << 2;

    auto fold = [&](int t, float* rm, float* cvo) {
        const float* Lr = wlds + 64 + t * 256;
        float4 v = *reinterpret_cast<const float4*>(Lr + bl);
        int offL = (lane == 0)  ? t       : (64 + t * 256 + bl - 1);
        int offR = (lane == 63) ? (6 + t) : (64 + t * 256 + bl + 4);
        float lraw = wlds[offL];
        float rraw = wlds[offR];
        float lf = (lane == 0  && !hasL) ? 0.f : lraw;
        float rg = (lane == 63 && !hasR) ? 0.f : rraw;
        rm[0] = fminf(lf,  fminf(v.x, v.y));
        rm[1] = fminf(v.x, fminf(v.y, v.z));
        rm[2] = fminf(v.y, fminf(v.z, v.w));
        rm[3] = fminf(v.z, fminf(v.w, rg));
        cvo[0] = v.x; cvo[1] = v.y; cvo[2] = v.z; cvo[3] = v.w;
    };

    float rm[6][4], cv[4][4], tmp[4];
    fold(0, rm[0], tmp);
    fold(1, rm[1], cv[0]);
    fold(2, rm[2], cv[1]);
    fold(3, rm[3], cv[2]);
    fold(4, rm[4], cv[3]);
    fold(5, rm[5], tmp);
    if (r0 == 0)         { rm[0][0] = rm[0][1] = rm[0][2] = rm[0][3] = 0.f; }
    if (r0 == IMG_H - 4) { rm[5][0] = rm[5][1] = rm[5][2] = rm[5][3] = 0.f; }

    // bt (stride-1 boundary map): bt = (g == 1) && (min3x3 == 0)
    float bt[4][4];
    #pragma unroll
    for (int r = 0; r < 4; ++r)
        #pragma unroll
        for (int k = 0; k < 4; ++k) {
            float cm = fminf(rm[r][k], fminf(rm[r + 1][k], rm[r + 2][k]));
            bt[r][k] = (cv[r][k] > 0.5f && cm < 0.5f) ? 1.f : 0.f;
        }

    // bt4 center = (r0, jg) = bt[0][0]; bt2 = bt(r0+(r&~1), jg+(k&~1))
    const float wb4 = w2 * bt[0][0];
    float base2[2][2];
    base2[0][0] = fmaf(w1, bt[0][0], wb4);
    base2[0][1] = fmaf(w1, bt[0][2], wb4);
    base2[1][0] = fmaf(w1, bt[2][0], wb4);
    base2[1][1] = fmaf(w1, bt[2][2], wb4);

    // Per-pixel: f = w0*bt + base2;  t = f > 0.1
    // bce_px = ln2*log2(1+e^x) - x*t ; p = u/(1+u), u = e^x
    // sum_t via ballot+popcount (SALU). Dual accumulators (row parity).
    float l2[2]  = {0.f, 0.f}, xt[2] = {0.f, 0.f};
    float itr[2] = {0.f, 0.f}, sp[2] = {0.f, 0.f};
    int st = 0;

    auto px = [&](float x, float btv, float b2v, int a) {
        float f = fmaf(w0, btv, b2v);
        bool  c = f > 0.1f;
        st += (int)__popcll(__ballot(c));
        float u   = __builtin_amdgcn_exp2f(x * LOG2E);   // e^x
        float opu = 1.f + u;
        float p   = u * __builtin_amdgcn_rcpf(opu);      // sigmoid(x)
        l2[a]  += __builtin_amdgcn_logf(opu);            // log2(1+e^x)
        sp[a]  += p;
        xt[a]  += c ? x : 0.f;
        itr[a] += c ? p : 0.f;
    };

    #pragma unroll
    for (int r = 0; r < 4; ++r) {
        const float bA = base2[r >> 1][0];
        const float bB = base2[r >> 1][1];
        px(xv[r].x, bt[r][0], bA, r & 1);
        px(xv[r].y, bt[r][1], bA, r & 1);
        px(xv[r].z, bt[r][2], bB, r & 1);
        px(xv[r].w, bt[r][3], bB, r & 1);
    }

    float bce   = fmaf(LN2, l2[0] + l2[1], -(xt[0] + xt[1]));
    float inter = itr[0] + itr[1];
    float sump  = sp[0] + sp[1];

    // wave64 reduce; lane 0 stores the wave's partial. No barriers.
    #pragma unroll
    for (int off = 32; off > 0; off >>= 1) {
        bce   += __shfl_down(bce, off);
        inter += __shfl_down(inter, off);
        sump  += __shfl_down(sump, off);
    }
    if (lane == 0) {
        float4 o; o.x = bce; o.y = inter; o.z = sump; o.w = (float)st;
        ws4[(b << 2) | wid] = o;
    }
}

// 1 block, 1024 threads. Thread t sums slots [16t, 16t+16); wave w (threads
// 64w..64w+63) covers slots [1024w, 1024w+1024) == exactly image w.
__global__ __launch_bounds__(1024) void dal_finalize(
    const float4* __restrict__ ws4, float* __restrict__ out)
{
    const int t    = (int)threadIdx.x;
    const int wv   = t >> 6;      // wave id == image id
    const int lane = t & 63;
    const int i0   = t * 16;

    float bce = 0.f, inter = 0.f, sump = 0.f, sumt = 0.f;
    #pragma unroll
    for (int i = 0; i < 16; ++i) {
        float4 a = ws4[i0 + i];
        bce += a.x; inter += a.y; sump += a.z; sumt += a.w;
    }

    #pragma unroll
    for (int off = 32; off > 0; off >>= 1) {
        bce   += __shfl_down(bce, off);
        inter += __shfl_down(inter, off);
        sump  += __shfl_down(sump, off);
        sumt  += __shfl_down(sumt, off);
    }

    __shared__ float sb[16], sd[16];
    if (lane == 0) {
        sb[wv] = bce;
        sd[wv] = 1.f - (2.f * inter + 1.f) / (sump + sumt + 1.f);
    }
    __syncthreads();
    if (t == 0) {
        float tb = 0.f, td = 0.f;
        #pragma unroll
        for (int i = 0; i < NIMG; ++i) { tb += sb[i]; td += sd[i]; }
        out[0] = tb / NPIX;
        out[1] = td / (float)NIMG;
    }
}

extern "C" void kernel_launch(void* const* d_in, const int* in_sizes, int n_in,
                              void* d_out, int out_size, void* d_ws, size_t ws_size,
                              hipStream_t stream)
{
    const float* x    = (const float*)d_in[0];  // boundary_logits [16,1,1024,1024]
    const float* g    = (const float*)d_in[1];  // gtmasks        [16,1024,1024]
    const float* fuse = (const float*)d_in[2];  // fuse_kernel    [3]
    float* out = (float*)d_out;
    float4* ws4 = (float4*)d_ws;

    dal_main<<<NBLK, 256, 0, stream>>>(x, g, fuse, ws4);
    dal_finalize<<<1, 1024, 0, stream>>>(ws4, out);
}